// Round 5
// baseline (2020.422 us; speedup 1.0000x reference)
//
#include <hip/hip_runtime.h>

#define NROWS 50000
#define DIM   256
#define SHOPS 6
#define ROUNDS 4
#define EPSV  1e-5f
#define ND ((size_t)NROWS * DIM)
#define NB  196                              // ceil(NROWS/256)

typedef _Float16 f16x8 __attribute__((ext_vector_type(8)));
typedef _Float16 f16x4 __attribute__((ext_vector_type(4)));
typedef float    f32x4 __attribute__((ext_vector_type(4)));

#define GLDS16(GP, LP) \
    __builtin_amdgcn_global_load_lds((const __attribute__((address_space(1))) unsigned*)(GP), \
                                     (__attribute__((address_space(3))) unsigned*)(LP), 16, 0, 0)

// ---------------------------------------------------------------------------
// Multi-slot fp16 MFMA GEMM: C[z] = A @ W[base_slot+z]^T for z in [0, zcount).
// Grid (391, 2, 1); 4 waves (2x2); tile 128x128; 16x16x32 MFMA.
// A fragments for the FULL K=256 held in registers (loaded once per block);
// W staged in LDS, double-buffered, XOR-swizzled via pre-swizzled global src.
// MFMA operands SWAPPED (bf first) so lane holds 4 consecutive output cols:
//   out_row = bm0 + wm*64 + mt*16 + (l&15)
//   out_col = bn0 + wn*64 + nt*16 + (l>>4)*4 + j   -> 8B f16x4 stores.
// ---------------------------------------------------------------------------
__global__ __launch_bounds__(256, 2)
void gemm_ms(const _Float16* __restrict__ A, const _Float16* __restrict__ WH,
             int base_slot, int zcount, _Float16* __restrict__ C16)
{
    __shared__ _Float16 wlds[2][8192];       // 2 x 16KB W k-chunk buffers
    const int tid  = threadIdx.x;
    const int l    = tid & 63;
    const int w    = tid >> 6;
    const int wm   = w & 1;
    const int wn   = w >> 1;
    const int bm0  = blockIdx.x * 128;
    const int bn0  = blockIdx.y * 128;
    const int lrow = l & 15;
    const int koct = l >> 4;                 // 0..3

    // ---- A fragments, full K, in registers (static indexing only) ----
    f16x8 af[4][8];
    #pragma unroll
    for (int mt = 0; mt < 4; ++mt) {
        const int ar = min(bm0 + wm * 64 + mt * 16 + lrow, NROWS - 1);
        const char* rp = (const char*)A + (size_t)ar * 512 + koct * 16;
        #pragma unroll
        for (int ks = 0; ks < 8; ++ks)
            af[mt][ks] = *(const f16x8*)(rp + ks * 64);
    }

    const int total = zcount * 4;            // k-steps of 64 across all slots

    // stage step's 16KB W chunk (rows bn0..bn0+127, k kt..kt+64) into wlds[buf]
    auto stage = [&](int step, int buf) {
        const int z  = step >> 2;
        const int kt = (step & 3) * 64;
        const char* Wb = (const char*)(WH + (size_t)(base_slot + z) * (DIM * DIM));
        #pragma unroll
        for (int q = 0; q < 4; ++q) {
            const int f    = (w * 4 + q) * 64 + l;     // 16B chunk id 0..1023
            const int row  = f >> 3;                   // 0..127
            const int slog = (f & 7) ^ (row & 7);      // inverse-swizzled slot
            GLDS16(Wb + (size_t)(bn0 + row) * 512 + kt * 2 + slog * 16,
                   (char*)(&wlds[buf][0]) + (w * 4 + q) * 1024);
        }
    };

    f32x4 acc[4][4];
    int cur = 0;
    stage(0, 0);

    for (int z = 0; z < zcount; ++z) {
        #pragma unroll
        for (int mt = 0; mt < 4; ++mt)
            #pragma unroll
            for (int nt = 0; nt < 4; ++nt)
                acc[mt][nt] = (f32x4){0.f, 0.f, 0.f, 0.f};

        #pragma unroll
        for (int kt = 0; kt < 4; ++kt) {
            // sync: drains stage(step) issued last iter; frees buf cur^1
            __syncthreads();
            const int step = z * 4 + kt;
            if (step + 1 < total) stage(step + 1, cur ^ 1);  // stays in flight

            const char* ldsb = (const char*)&wlds[cur][0];
            #pragma unroll
            for (int ks = 0; ks < 2; ++ks) {
                f16x8 bf[4];
                const int slot = koct + ks * 4;
                #pragma unroll
                for (int nt = 0; nt < 4; ++nt) {
                    const int r = wn * 64 + nt * 16 + lrow;
                    bf[nt] = *(const f16x8*)(ldsb + r * 128 + ((slot ^ (r & 7)) << 4));
                }
                #pragma unroll
                for (int mt = 0; mt < 4; ++mt)
                    #pragma unroll
                    for (int nt = 0; nt < 4; ++nt)
                        acc[mt][nt] = __builtin_amdgcn_mfma_f32_16x16x32_f16(
                            bf[nt], af[mt][kt * 2 + ks], acc[mt][nt], 0, 0, 0);
            }
            cur ^= 1;
        }

        // ---- epilogue for slot z: 8B stores, 4 consecutive cols per lane ----
        const size_t zoff = (size_t)z * ND;
        const int ocol = bn0 + wn * 64 + koct * 4;
        #pragma unroll
        for (int mt = 0; mt < 4; ++mt) {
            const int orow = bm0 + wm * 64 + mt * 16 + lrow;
            if (orow < NROWS) {
                #pragma unroll
                for (int nt = 0; nt < 4; ++nt) {
                    f16x4 o;
                    o[0] = (_Float16)acc[mt][nt][0];
                    o[1] = (_Float16)acc[mt][nt][1];
                    o[2] = (_Float16)acc[mt][nt][2];
                    o[3] = (_Float16)acc[mt][nt][3];
                    *(f16x4*)(C16 + zoff + (size_t)orow * DIM + ocol + nt * 16) = o;
                }
            }
        }
    }
}

// ---------------------------------------------------------------------------
__global__ __launch_bounds__(256)
void convert_w(const float* __restrict__ Wctr, const float* __restrict__ Wctr2,
               const float* __restrict__ Wpre, const float* __restrict__ Wsuc,
               _Float16* __restrict__ WH)
{
    const size_t i4 = (size_t)blockIdx.x * 256 + threadIdx.x;
    const size_t NT = (size_t)56 * DIM * DIM / 4;
    if (i4 >= NT) return;
    const size_t e = i4 * 4;
    const int slot = (int)(e >> 16);
    const int off  = (int)(e & 65535);
    const float* src;
    if (slot < 48) {
        const int r = slot / 12, s = slot % 12, k = s >> 1, dir = s & 1;
        src = (dir ? Wsuc : Wpre) + (((size_t)r * SHOPS + k) << 16) + off;
    } else if (slot < 52) {
        src = Wctr + ((size_t)(slot - 48) << 16) + off;
    } else {
        src = Wctr2 + ((size_t)(slot - 52) << 16) + off;
    }
    const float4 v = *(const float4*)src;
    f16x4 h;
    h[0] = (_Float16)v.x; h[1] = (_Float16)v.y;
    h[2] = (_Float16)v.z; h[3] = (_Float16)v.w;
    *(f16x4*)(WH + e) = h;
}

__global__ __launch_bounds__(256)
void init_x(const float* __restrict__ lane, float* __restrict__ X,
            _Float16* __restrict__ Xh)
{
    const size_t i4 = (size_t)blockIdx.x * 256 + threadIdx.x;
    if (i4 >= ND / 4) return;
    const float4 v = *(const float4*)(lane + i4 * 4);
    *(float4*)(X + i4 * 4) = v;
    f16x4 h;
    h[0] = (_Float16)v.x; h[1] = (_Float16)v.y;
    h[2] = (_Float16)v.z; h[3] = (_Float16)v.w;
    *(f16x4*)(Xh + i4 * 4) = h;
}

// x = relu(gn(y)*w+b + res) -> X fp32 + Xh fp16
__global__ __launch_bounds__(256)
void gn1_kernel(const _Float16* __restrict__ inh, const float* __restrict__ w,
                const float* __restrict__ b, float* __restrict__ X,
                _Float16* __restrict__ Xh)
{
    const int lane = threadIdx.x & 63;
    const int wv   = threadIdx.x >> 6;
    const int row  = blockIdx.x * 4 + wv;
    if (row >= NROWS) return;

    const f16x4 hv = *(const f16x4*)(inh + (size_t)row * DIM + lane * 4);
    float4 v;
    v.x = (float)hv[0]; v.y = (float)hv[1]; v.z = (float)hv[2]; v.w = (float)hv[3];
    float s  = v.x + v.y + v.z + v.w;
    float ss = v.x * v.x + v.y * v.y + v.z * v.z + v.w * v.w;
    #pragma unroll
    for (int off = 32; off >= 1; off >>= 1) {
        s  += __shfl_xor(s, off);
        ss += __shfl_xor(ss, off);
    }
    const float m   = s * (1.0f / DIM);
    const float var = ss * (1.0f / DIM) - m * m;
    const float inv = rsqrtf(var + EPSV);

    const float4 wv4 = *(const float4*)(w + lane * 4);
    const float4 bv4 = *(const float4*)(b + lane * 4);
    const float4 r4  = *(const float4*)(X + (size_t)row * DIM + lane * 4);
    float4 o;
    o.x = fmaxf((v.x - m) * inv * wv4.x + bv4.x + r4.x, 0.f);
    o.y = fmaxf((v.y - m) * inv * wv4.y + bv4.y + r4.y, 0.f);
    o.z = fmaxf((v.z - m) * inv * wv4.z + bv4.z + r4.z, 0.f);
    o.w = fmaxf((v.w - m) * inv * wv4.w + bv4.w + r4.w, 0.f);
    *(float4*)(X + (size_t)row * DIM + lane * 4) = o;
    f16x4 oh;
    oh[0] = (_Float16)o.x; oh[1] = (_Float16)o.y;
    oh[2] = (_Float16)o.z; oh[3] = (_Float16)o.w;
    *(f16x4*)(Xh + (size_t)row * DIM + lane * 4) = oh;
}

// ---------------------------------------------------------------------------
// CSR inversion (once per launch; indices constant across rounds)
// ---------------------------------------------------------------------------
__global__ __launch_bounds__(256)
void count_kernel(const int* __restrict__ pidx, const int* __restrict__ sidx,
                  int* __restrict__ counts)
{
    const int i = blockIdx.x * 256 + threadIdx.x;
    if (i >= NROWS) return;
    const int s = blockIdx.y;
    const int k = s >> 1, dir = s & 1;
    const int* scp = (dir ? pidx : sidx) + k * NROWS;
    atomicAdd(&counts[scp[i]], 1);
}

__global__ __launch_bounds__(256)
void scan1_kernel(const int* __restrict__ counts, int* __restrict__ offs,
                  int* __restrict__ bsum)
{
    __shared__ int wsum[4];
    const int tid = threadIdx.x, lane = tid & 63, wv = tid >> 6;
    const int i = blockIdx.x * 256 + tid;
    const int c = (i < NROWS) ? counts[i] : 0;
    int v = c;
    #pragma unroll
    for (int off = 1; off < 64; off <<= 1) {
        const int t = __shfl_up(v, off);
        if (lane >= off) v += t;
    }
    if (lane == 63) wsum[wv] = v;
    __syncthreads();
    int add = 0;
    for (int w = 0; w < wv; ++w) add += wsum[w];
    if (i < NROWS) offs[i] = add + v - c;
    if (tid == 255) bsum[blockIdx.x] = wsum[0] + wsum[1] + wsum[2] + wsum[3];
}

__global__ __launch_bounds__(256)
void scan2_kernel(const int* __restrict__ bsum, int* __restrict__ bpre)
{
    __shared__ int wsum[4];
    const int tid = threadIdx.x, lane = tid & 63, wv = tid >> 6;
    const int c = (tid < NB) ? bsum[tid] : 0;
    int v = c;
    #pragma unroll
    for (int off = 1; off < 64; off <<= 1) {
        const int t = __shfl_up(v, off);
        if (lane >= off) v += t;
    }
    if (lane == 63) wsum[wv] = v;
    __syncthreads();
    int add = 0;
    for (int w = 0; w < wv; ++w) add += wsum[w];
    if (tid < NB) bpre[tid] = add + v - c;
}

__global__ __launch_bounds__(256)
void scan3_kernel(int* __restrict__ offs, const int* __restrict__ bpre,
                  int* __restrict__ cursor)
{
    const int i = blockIdx.x * 256 + threadIdx.x;
    if (i < NROWS) {
        const int v = offs[i] + bpre[blockIdx.x];
        offs[i] = v;
        cursor[i] = v;
    }
    if (i == 0) offs[NROWS] = 12 * NROWS;
}

__global__ __launch_bounds__(256)
void fill_kernel(const int* __restrict__ pidx, const int* __restrict__ sidx,
                 const int* __restrict__ nhp, const int* __restrict__ nhs,
                 int* __restrict__ cursor, int* __restrict__ entries)
{
    const int i = blockIdx.x * 256 + threadIdx.x;
    if (i >= NROWS) return;
    const int s = blockIdx.y;
    const int k = s >> 1, dir = s & 1;
    const int* scp = (dir ? pidx : sidx) + k * NROWS;
    const int* gp  = (dir ? nhs  : nhp)  + k * NROWS;
    const int pos = atomicAdd(&cursor[scp[i]], 1);
    entries[pos] = (s << 16) | gp[i];
}

// ---------------------------------------------------------------------------
// combine: acc = (FIRST ? YC[r] : TEMP16[r]) + sum of Y rows for entries with
// seg in [c0, c0+nch). LAST: fused GroupNorm+ReLU -> Hh. else -> TEMP16.
// ---------------------------------------------------------------------------
template<int FIRST, int LAST>
__global__ __launch_bounds__(256)
void combine_f16(const _Float16* __restrict__ YC, _Float16* __restrict__ TEMP16,
                 const _Float16* __restrict__ YB,
                 const int* __restrict__ offsets, const int* __restrict__ entries,
                 int c0, int nch,
                 const float* __restrict__ gw, const float* __restrict__ gb,
                 _Float16* __restrict__ Hh)
{
    const int lane = threadIdx.x & 63;
    const int wv   = threadIdx.x >> 6;
    const int r    = blockIdx.x * 4 + wv;
    if (r >= NROWS) return;
    const size_t rowoff = (size_t)r * DIM + lane * 4;

    const f16x4 iv = FIRST ? *(const f16x4*)(YC + rowoff)
                           : *(const f16x4*)(TEMP16 + rowoff);
    float4 acc;
    acc.x = (float)iv[0]; acc.y = (float)iv[1];
    acc.z = (float)iv[2]; acc.w = (float)iv[3];

    const int e0 = offsets[r], e1 = offsets[r + 1];
    for (int e = e0; e < e1; ++e) {
        const int ent = entries[e];
        const int s = ent >> 16;
        if ((unsigned)(s - c0) < (unsigned)nch) {
            const f16x4 yv = *(const f16x4*)(YB + (size_t)(s - c0) * ND
                                             + (size_t)(ent & 0xFFFF) * DIM + lane * 4);
            acc.x += (float)yv[0]; acc.y += (float)yv[1];
            acc.z += (float)yv[2]; acc.w += (float)yv[3];
        }
    }

    if (LAST) {
        float s  = acc.x + acc.y + acc.z + acc.w;
        float ss = acc.x * acc.x + acc.y * acc.y + acc.z * acc.z + acc.w * acc.w;
        #pragma unroll
        for (int off = 32; off >= 1; off >>= 1) {
            s  += __shfl_xor(s, off);
            ss += __shfl_xor(ss, off);
        }
        const float m   = s * (1.0f / DIM);
        const float var = ss * (1.0f / DIM) - m * m;
        const float inv = rsqrtf(var + EPSV);
        const float4 wv4 = *(const float4*)(gw + lane * 4);
        const float4 bv4 = *(const float4*)(gb + lane * 4);
        f16x4 o;
        o[0] = (_Float16)fmaxf((acc.x - m) * inv * wv4.x + bv4.x, 0.f);
        o[1] = (_Float16)fmaxf((acc.y - m) * inv * wv4.y + bv4.y, 0.f);
        o[2] = (_Float16)fmaxf((acc.z - m) * inv * wv4.z + bv4.z, 0.f);
        o[3] = (_Float16)fmaxf((acc.w - m) * inv * wv4.w + bv4.w, 0.f);
        *(f16x4*)(Hh + rowoff) = o;
    } else {
        f16x4 o;
        o[0] = (_Float16)acc.x; o[1] = (_Float16)acc.y;
        o[2] = (_Float16)acc.z; o[3] = (_Float16)acc.w;
        *(f16x4*)(TEMP16 + rowoff) = o;
    }
}

// ---------------------------------------------------------------------------
extern "C" void kernel_launch(void* const* d_in, const int* in_sizes, int n_in,
                              void* d_out, int out_size, void* d_ws, size_t ws_size,
                              hipStream_t stream)
{
    const float* lane   = (const float*)d_in[0];
    const float* W_ctr  = (const float*)d_in[1];
    const float* norm_w = (const float*)d_in[2];
    const float* norm_b = (const float*)d_in[3];
    const float* W_ctr2 = (const float*)d_in[4];
    const float* c2w    = (const float*)d_in[5];
    const float* c2b    = (const float*)d_in[6];
    const float* W_pre  = (const float*)d_in[7];
    const float* W_suc  = (const float*)d_in[8];
    const int*   pidx   = (const int*)d_in[9];
    const int*   sidx   = (const int*)d_in[10];
    const int*   nhp    = (const int*)d_in[11];
    const int*   nhs    = (const int*)d_in[12];

    float* X = (float*)d_out;

    // ---- workspace layout ----
    char* p = (char*)d_ws;
    int* counts  = (int*)p; p += (size_t)NROWS * 4;
    int* offsets = (int*)p; p += (size_t)(NROWS + 4) * 4;
    int* cursor  = (int*)p; p += (size_t)NROWS * 4;
    int* bsum    = (int*)p; p += 256 * 4;
    int* bpre    = (int*)p; p += 256 * 4;
    int* entries = (int*)p; p += (size_t)12 * NROWS * 4;
    p = (char*)(((uintptr_t)p + 15) & ~(uintptr_t)15);
    _Float16* Xh   = (_Float16*)p; p += ND * 2;
    _Float16* Hh   = (_Float16*)p; p += ND * 2;
    _Float16* T16  = (_Float16*)p; p += ND * 2;
    _Float16* YC   = (_Float16*)p; p += ND * 2;
    _Float16* WH   = (_Float16*)p; p += (size_t)56 * DIM * DIM * 2;
    p = (char*)(((uintptr_t)p + 15) & ~(uintptr_t)15);
    _Float16* YBUF = (_Float16*)p;

    const size_t used = (size_t)(p - (char*)d_ws);
    int nslot = (int)((ws_size - used) / (ND * 2));
    if (nslot < 1) nslot = 1;
    int CH = nslot > 12 ? 12 : nslot;
    const int nchunks = (12 + CH - 1) / CH;
    CH = (12 + nchunks - 1) / nchunks;
    _Float16* Y2 = YBUF;   // ctr2 output reuses slot 0 (stream-ordered, safe)

    const dim3 blk(256);
    const dim3 gg(391, 2, 1);
    const int  gnBlocks = (NROWS + 3) / 4;
    const int  cwBlocks = (int)(((size_t)56 * DIM * DIM / 4 + 255) / 256);
    const int  ixBlocks = (int)((ND / 4 + 255) / 256);

    // one-time prep
    convert_w<<<cwBlocks, blk, 0, stream>>>(W_ctr, W_ctr2, W_pre, W_suc, WH);
    init_x<<<ixBlocks, blk, 0, stream>>>(lane, X, Xh);
    hipMemsetAsync(counts, 0, NROWS * sizeof(int), stream);
    count_kernel<<<dim3(NB, 12), blk, 0, stream>>>(pidx, sidx, counts);
    scan1_kernel<<<NB, blk, 0, stream>>>(counts, offsets, bsum);
    scan2_kernel<<<1, blk, 0, stream>>>(bsum, bpre);
    scan3_kernel<<<NB, blk, 0, stream>>>(offsets, bpre, cursor);
    fill_kernel<<<dim3(NB, 12), blk, 0, stream>>>(pidx, sidx, nhp, nhs,
                                                  cursor, entries);

    for (int i = 0; i < ROUNDS; ++i) {
        // YC = x @ W_ctr[i].T
        gemm_ms<<<gg, blk, 0, stream>>>(Xh, WH, 48 + i, 1, YC);
        // 12 message GEMMs + combine (last chunk fuses GN+ReLU -> Hh)
        for (int c0 = 0; c0 < 12; c0 += CH) {
            const int nz = (12 - c0 < CH) ? (12 - c0) : CH;
            gemm_ms<<<gg, blk, 0, stream>>>(Xh, WH, i * 12 + c0, nz, YBUF);
            const bool first = (c0 == 0);
            const bool last  = (c0 + nz >= 12);
            if (first && last)
                combine_f16<1, 1><<<gnBlocks, blk, 0, stream>>>(YC, T16, YBUF,
                    offsets, entries, c0, nz, norm_w + i * DIM, norm_b + i * DIM, Hh);
            else if (first)
                combine_f16<1, 0><<<gnBlocks, blk, 0, stream>>>(YC, T16, YBUF,
                    offsets, entries, c0, nz, norm_w + i * DIM, norm_b + i * DIM, Hh);
            else if (last)
                combine_f16<0, 1><<<gnBlocks, blk, 0, stream>>>(YC, T16, YBUF,
                    offsets, entries, c0, nz, norm_w + i * DIM, norm_b + i * DIM, Hh);
            else
                combine_f16<0, 0><<<gnBlocks, blk, 0, stream>>>(YC, T16, YBUF,
                    offsets, entries, c0, nz, norm_w + i * DIM, norm_b + i * DIM, Hh);
        }
        // y = h @ W_ctr2[i].T
        gemm_ms<<<gg, blk, 0, stream>>>(Hh, WH, 52 + i, 1, Y2);
        // x = relu(gn(y) + x)
        gn1_kernel<<<gnBlocks, blk, 0, stream>>>(Y2, c2w + i * DIM,
                                                 c2b + i * DIM, X, Xh);
    }
}

// Round 6
// 1517.797 us; speedup vs baseline: 1.3312x; 1.3312x over previous
//
#include <hip/hip_runtime.h>

#define NROWS 50000
#define DIM   256
#define SHOPS 6
#define ROUNDS 4
#define EPSV  1e-5f
#define ND ((size_t)NROWS * DIM)
#define NB  196                              // ceil(NROWS/256)

typedef _Float16 f16x8 __attribute__((ext_vector_type(8)));
typedef _Float16 f16x4 __attribute__((ext_vector_type(4)));
typedef float    f32x4 __attribute__((ext_vector_type(4)));

#define GLDS16(GP, LP) \
    __builtin_amdgcn_global_load_lds((const __attribute__((address_space(1))) unsigned*)(GP), \
                                     (__attribute__((address_space(3))) unsigned*)(LP), 16, 0, 0)

__device__ __forceinline__ int imin(int a, int b) { return a < b ? a : b; }

// ---------------------------------------------------------------------------
// Pipelined fp16 MFMA GEMM: C[z] = A @ W[base_slot+z]^T.
// Linear grid nwg = 391*2*nz, bijectively chunked to XCDs (m204) with
// same-bx blocks contiguous -> A tile is L2-resident per XCD.
// 128x128 tile, 4 waves (2x2), BK=32, 8 k-steps, 16x16x32 MFMA.
// 3-buffer LDS pipeline, counted vmcnt(4) (= 1 stage of 4 loads in flight),
// raw s_barrier; stage(t+2) issued right after barrier(t).
// LDS swizzle: 64B rows, phys_slot = slot ^ ((row>>1)&3); applied on the
// pre-swizzled global SOURCE (linear LDS dest) and on the ds_read (rule 21).
// ---------------------------------------------------------------------------
__global__ __launch_bounds__(256)
void gemm_p(const _Float16* __restrict__ A, const _Float16* __restrict__ WH,
            int base_slot, int nz, _Float16* __restrict__ C16, int nwg)
{
    __shared__ _Float16 lds[3][8192];        // 3 x (A 8KB + W 8KB) = 48KB
    char* ldsb = (char*)lds;

    // bijective XCD chunking: consecutive g on same XCD; g is bx-major.
    const int bid = blockIdx.x;
    const int q   = nwg >> 3, r = nwg & 7;
    const int xcd = bid & 7,  ii = bid >> 3;
    const int g   = (xcd < r) ? xcd * (q + 1) + ii
                              : r * (q + 1) + (xcd - r) * q + ii;
    const int bx  = g / (2 * nz);
    const int sub = g - bx * 2 * nz;
    const int by  = sub & 1;
    const size_t z = sub >> 1;

    const int tid = threadIdx.x;
    const int l   = tid & 63;
    const int w   = tid >> 6;
    const int wm  = w & 1;
    const int wn  = w >> 1;
    const int bm0 = bx * 128;
    const int bn0 = by * 128;
    const int lr  = l & 15;
    const int sl  = l >> 4;                  // logical 16B k-slot 0..3

    const char* Ab = (const char*)A;
    const char* Wb = (const char*)(WH + (size_t)(base_slot + z) * (DIM * DIM));

    f32x4 acc[4][4];
    #pragma unroll
    for (int mt = 0; mt < 4; ++mt)
        #pragma unroll
        for (int nt = 0; nt < 4; ++nt)
            acc[mt][nt] = (f32x4){0.f, 0.f, 0.f, 0.f};

    // stage k-step `step` (32 k-elems = 64B per row) into buffer `buf`.
    // 4 gload_lds per wave (2 A + 2 W). Dest linear; source inverse-swizzled.
    auto stage = [&](int step, int buf) {
        const int kt64 = step * 64;
        char* base = ldsb + buf * 16384;
        #pragma unroll
        for (int qq = 0; qq < 2; ++qq) {
            const int c    = (w * 2 + qq) * 64 + l;   // 16B chunk 0..511
            const int row  = c >> 2;                  // 0..127
            const int slog = (c & 3) ^ ((row >> 1) & 3);
            const int ar   = imin(bm0 + row, NROWS - 1);
            GLDS16(Ab + (size_t)ar * 512 + kt64 + slog * 16,
                   base + (w * 2 + qq) * 1024);
            GLDS16(Wb + (size_t)(bn0 + row) * 512 + kt64 + slog * 16,
                   base + 8192 + (w * 2 + qq) * 1024);
        }
    };

    auto compute = [&](int buf) {
        const char* base = ldsb + buf * 16384;
        f16x8 af[4], bf[4];
        #pragma unroll
        for (int mt = 0; mt < 4; ++mt) {
            const int row = wm * 64 + mt * 16 + lr;
            af[mt] = *(const f16x8*)(base + row * 64 + ((sl ^ ((row >> 1) & 3)) << 4));
        }
        #pragma unroll
        for (int nt = 0; nt < 4; ++nt) {
            const int row = wn * 64 + nt * 16 + lr;
            bf[nt] = *(const f16x8*)(base + 8192 + row * 64 + ((sl ^ ((row >> 1) & 3)) << 4));
        }
        #pragma unroll
        for (int mt = 0; mt < 4; ++mt)
            #pragma unroll
            for (int nt = 0; nt < 4; ++nt)
                acc[mt][nt] = __builtin_amdgcn_mfma_f32_16x16x32_f16(
                    af[mt], bf[nt], acc[mt][nt], 0, 0, 0);
    };

    stage(0, 0);
    stage(1, 1);

    #pragma unroll
    for (int t = 0; t < 7; ++t) {
        asm volatile("s_waitcnt vmcnt(4)" ::: "memory");   // stage(t) landed
        __builtin_amdgcn_s_barrier();                       // all waves ready
        __builtin_amdgcn_sched_barrier(0);                  // pin order
        if (t < 6) stage(t + 2, (t + 2) % 3);               // stays in flight
        compute(t % 3);
    }
    asm volatile("s_waitcnt vmcnt(0)" ::: "memory");        // last stage
    __builtin_amdgcn_s_barrier();
    __builtin_amdgcn_sched_barrier(0);
    compute(7 % 3);

    // epilogue: identical mapping to the verified round-4 kernel
    const int colb = bn0 + wn * 64 + lr;
    #pragma unroll
    for (int mt = 0; mt < 4; ++mt) {
        #pragma unroll
        for (int j = 0; j < 4; ++j) {
            const int row = bm0 + wm * 64 + mt * 16 + sl * 4 + j;
            if (row < NROWS) {
                #pragma unroll
                for (int nt = 0; nt < 4; ++nt)
                    C16[z * ND + (size_t)row * DIM + colb + nt * 16] =
                        (_Float16)acc[mt][nt][j];
            }
        }
    }
}

// ---------------------------------------------------------------------------
__global__ __launch_bounds__(256)
void convert_w(const float* __restrict__ Wctr, const float* __restrict__ Wctr2,
               const float* __restrict__ Wpre, const float* __restrict__ Wsuc,
               _Float16* __restrict__ WH)
{
    const size_t i4 = (size_t)blockIdx.x * 256 + threadIdx.x;
    const size_t NT = (size_t)56 * DIM * DIM / 4;
    if (i4 >= NT) return;
    const size_t e = i4 * 4;
    const int slot = (int)(e >> 16);
    const int off  = (int)(e & 65535);
    const float* src;
    if (slot < 48) {
        const int r = slot / 12, s = slot % 12, k = s >> 1, dir = s & 1;
        src = (dir ? Wsuc : Wpre) + (((size_t)r * SHOPS + k) << 16) + off;
    } else if (slot < 52) {
        src = Wctr + ((size_t)(slot - 48) << 16) + off;
    } else {
        src = Wctr2 + ((size_t)(slot - 52) << 16) + off;
    }
    const float4 v = *(const float4*)src;
    f16x4 h;
    h[0] = (_Float16)v.x; h[1] = (_Float16)v.y;
    h[2] = (_Float16)v.z; h[3] = (_Float16)v.w;
    *(f16x4*)(WH + e) = h;
}

__global__ __launch_bounds__(256)
void init_x(const float* __restrict__ lane, float* __restrict__ X,
            _Float16* __restrict__ Xh)
{
    const size_t i4 = (size_t)blockIdx.x * 256 + threadIdx.x;
    if (i4 >= ND / 4) return;
    const float4 v = *(const float4*)(lane + i4 * 4);
    *(float4*)(X + i4 * 4) = v;
    f16x4 h;
    h[0] = (_Float16)v.x; h[1] = (_Float16)v.y;
    h[2] = (_Float16)v.z; h[3] = (_Float16)v.w;
    *(f16x4*)(Xh + i4 * 4) = h;
}

// x = relu(gn(y)*w+b + res) -> X fp32 + Xh fp16
__global__ __launch_bounds__(256)
void gn1_kernel(const _Float16* __restrict__ inh, const float* __restrict__ w,
                const float* __restrict__ b, float* __restrict__ X,
                _Float16* __restrict__ Xh)
{
    const int lane = threadIdx.x & 63;
    const int wv   = threadIdx.x >> 6;
    const int row  = blockIdx.x * 4 + wv;
    if (row >= NROWS) return;

    const f16x4 hv = *(const f16x4*)(inh + (size_t)row * DIM + lane * 4);
    float4 v;
    v.x = (float)hv[0]; v.y = (float)hv[1]; v.z = (float)hv[2]; v.w = (float)hv[3];
    float s  = v.x + v.y + v.z + v.w;
    float ss = v.x * v.x + v.y * v.y + v.z * v.z + v.w * v.w;
    #pragma unroll
    for (int off = 32; off >= 1; off >>= 1) {
        s  += __shfl_xor(s, off);
        ss += __shfl_xor(ss, off);
    }
    const float m   = s * (1.0f / DIM);
    const float var = ss * (1.0f / DIM) - m * m;
    const float inv = rsqrtf(var + EPSV);

    const float4 wv4 = *(const float4*)(w + lane * 4);
    const float4 bv4 = *(const float4*)(b + lane * 4);
    const float4 r4  = *(const float4*)(X + (size_t)row * DIM + lane * 4);
    float4 o;
    o.x = fmaxf((v.x - m) * inv * wv4.x + bv4.x + r4.x, 0.f);
    o.y = fmaxf((v.y - m) * inv * wv4.y + bv4.y + r4.y, 0.f);
    o.z = fmaxf((v.z - m) * inv * wv4.z + bv4.z + r4.z, 0.f);
    o.w = fmaxf((v.w - m) * inv * wv4.w + bv4.w + r4.w, 0.f);
    *(float4*)(X + (size_t)row * DIM + lane * 4) = o;
    f16x4 oh;
    oh[0] = (_Float16)o.x; oh[1] = (_Float16)o.y;
    oh[2] = (_Float16)o.z; oh[3] = (_Float16)o.w;
    *(f16x4*)(Xh + (size_t)row * DIM + lane * 4) = oh;
}

// ---------------------------------------------------------------------------
// CSR inversion (once per launch; indices constant across rounds)
// ---------------------------------------------------------------------------
__global__ __launch_bounds__(256)
void count_kernel(const int* __restrict__ pidx, const int* __restrict__ sidx,
                  int* __restrict__ counts)
{
    const int i = blockIdx.x * 256 + threadIdx.x;
    if (i >= NROWS) return;
    const int s = blockIdx.y;
    const int k = s >> 1, dir = s & 1;
    const int* scp = (dir ? pidx : sidx) + k * NROWS;
    atomicAdd(&counts[scp[i]], 1);
}

__global__ __launch_bounds__(256)
void scan1_kernel(const int* __restrict__ counts, int* __restrict__ offs,
                  int* __restrict__ bsum)
{
    __shared__ int wsum[4];
    const int tid = threadIdx.x, lane = tid & 63, wv = tid >> 6;
    const int i = blockIdx.x * 256 + tid;
    const int c = (i < NROWS) ? counts[i] : 0;
    int v = c;
    #pragma unroll
    for (int off = 1; off < 64; off <<= 1) {
        const int t = __shfl_up(v, off);
        if (lane >= off) v += t;
    }
    if (lane == 63) wsum[wv] = v;
    __syncthreads();
    int add = 0;
    for (int w = 0; w < wv; ++w) add += wsum[w];
    if (i < NROWS) offs[i] = add + v - c;
    if (tid == 255) bsum[blockIdx.x] = wsum[0] + wsum[1] + wsum[2] + wsum[3];
}

__global__ __launch_bounds__(256)
void scan2_kernel(const int* __restrict__ bsum, int* __restrict__ bpre)
{
    __shared__ int wsum[4];
    const int tid = threadIdx.x, lane = tid & 63, wv = tid >> 6;
    const int c = (tid < NB) ? bsum[tid] : 0;
    int v = c;
    #pragma unroll
    for (int off = 1; off < 64; off <<= 1) {
        const int t = __shfl_up(v, off);
        if (lane >= off) v += t;
    }
    if (lane == 63) wsum[wv] = v;
    __syncthreads();
    int add = 0;
    for (int w = 0; w < wv; ++w) add += wsum[w];
    if (tid < NB) bpre[tid] = add + v - c;
}

__global__ __launch_bounds__(256)
void scan3_kernel(int* __restrict__ offs, const int* __restrict__ bpre,
                  int* __restrict__ cursor)
{
    const int i = blockIdx.x * 256 + threadIdx.x;
    if (i < NROWS) {
        const int v = offs[i] + bpre[blockIdx.x];
        offs[i] = v;
        cursor[i] = v;
    }
    if (i == 0) offs[NROWS] = 12 * NROWS;
}

__global__ __launch_bounds__(256)
void fill_kernel(const int* __restrict__ pidx, const int* __restrict__ sidx,
                 const int* __restrict__ nhp, const int* __restrict__ nhs,
                 int* __restrict__ cursor, int* __restrict__ entries)
{
    const int i = blockIdx.x * 256 + threadIdx.x;
    if (i >= NROWS) return;
    const int s = blockIdx.y;
    const int k = s >> 1, dir = s & 1;
    const int* scp = (dir ? pidx : sidx) + k * NROWS;
    const int* gp  = (dir ? nhs  : nhp)  + k * NROWS;
    const int pos = atomicAdd(&cursor[scp[i]], 1);
    entries[pos] = (s << 16) | gp[i];
}

// ---------------------------------------------------------------------------
// combine: acc = (FIRST ? YC[r] : TEMP16[r]) + sum of Y rows for entries with
// seg in [c0, c0+nch). LAST: fused GroupNorm+ReLU -> Hh. else -> TEMP16.
// ---------------------------------------------------------------------------
template<int FIRST, int LAST>
__global__ __launch_bounds__(256)
void combine_f16(const _Float16* __restrict__ YC, _Float16* __restrict__ TEMP16,
                 const _Float16* __restrict__ YB,
                 const int* __restrict__ offsets, const int* __restrict__ entries,
                 int c0, int nch,
                 const float* __restrict__ gw, const float* __restrict__ gb,
                 _Float16* __restrict__ Hh)
{
    const int lane = threadIdx.x & 63;
    const int wv   = threadIdx.x >> 6;
    const int r    = blockIdx.x * 4 + wv;
    if (r >= NROWS) return;
    const size_t rowoff = (size_t)r * DIM + lane * 4;

    const f16x4 iv = FIRST ? *(const f16x4*)(YC + rowoff)
                           : *(const f16x4*)(TEMP16 + rowoff);
    float4 acc;
    acc.x = (float)iv[0]; acc.y = (float)iv[1];
    acc.z = (float)iv[2]; acc.w = (float)iv[3];

    const int e0 = offsets[r], e1 = offsets[r + 1];
    for (int e = e0; e < e1; ++e) {
        const int ent = entries[e];
        const int s = ent >> 16;
        if ((unsigned)(s - c0) < (unsigned)nch) {
            const f16x4 yv = *(const f16x4*)(YB + (size_t)(s - c0) * ND
                                             + (size_t)(ent & 0xFFFF) * DIM + lane * 4);
            acc.x += (float)yv[0]; acc.y += (float)yv[1];
            acc.z += (float)yv[2]; acc.w += (float)yv[3];
        }
    }

    if (LAST) {
        float s  = acc.x + acc.y + acc.z + acc.w;
        float ss = acc.x * acc.x + acc.y * acc.y + acc.z * acc.z + acc.w * acc.w;
        #pragma unroll
        for (int off = 32; off >= 1; off >>= 1) {
            s  += __shfl_xor(s, off);
            ss += __shfl_xor(ss, off);
        }
        const float m   = s * (1.0f / DIM);
        const float var = ss * (1.0f / DIM) - m * m;
        const float inv = rsqrtf(var + EPSV);
        const float4 wv4 = *(const float4*)(gw + lane * 4);
        const float4 bv4 = *(const float4*)(gb + lane * 4);
        f16x4 o;
        o[0] = (_Float16)fmaxf((acc.x - m) * inv * wv4.x + bv4.x, 0.f);
        o[1] = (_Float16)fmaxf((acc.y - m) * inv * wv4.y + bv4.y, 0.f);
        o[2] = (_Float16)fmaxf((acc.z - m) * inv * wv4.z + bv4.z, 0.f);
        o[3] = (_Float16)fmaxf((acc.w - m) * inv * wv4.w + bv4.w, 0.f);
        *(f16x4*)(Hh + rowoff) = o;
    } else {
        f16x4 o;
        o[0] = (_Float16)acc.x; o[1] = (_Float16)acc.y;
        o[2] = (_Float16)acc.z; o[3] = (_Float16)acc.w;
        *(f16x4*)(TEMP16 + rowoff) = o;
    }
}

// ---------------------------------------------------------------------------
extern "C" void kernel_launch(void* const* d_in, const int* in_sizes, int n_in,
                              void* d_out, int out_size, void* d_ws, size_t ws_size,
                              hipStream_t stream)
{
    const float* lane   = (const float*)d_in[0];
    const float* W_ctr  = (const float*)d_in[1];
    const float* norm_w = (const float*)d_in[2];
    const float* norm_b = (const float*)d_in[3];
    const float* W_ctr2 = (const float*)d_in[4];
    const float* c2w    = (const float*)d_in[5];
    const float* c2b    = (const float*)d_in[6];
    const float* W_pre  = (const float*)d_in[7];
    const float* W_suc  = (const float*)d_in[8];
    const int*   pidx   = (const int*)d_in[9];
    const int*   sidx   = (const int*)d_in[10];
    const int*   nhp    = (const int*)d_in[11];
    const int*   nhs    = (const int*)d_in[12];

    float* X = (float*)d_out;

    // ---- workspace layout ----
    char* p = (char*)d_ws;
    int* counts  = (int*)p; p += (size_t)NROWS * 4;
    int* offsets = (int*)p; p += (size_t)(NROWS + 4) * 4;
    int* cursor  = (int*)p; p += (size_t)NROWS * 4;
    int* bsum    = (int*)p; p += 256 * 4;
    int* bpre    = (int*)p; p += 256 * 4;
    int* entries = (int*)p; p += (size_t)12 * NROWS * 4;
    p = (char*)(((uintptr_t)p + 15) & ~(uintptr_t)15);
    _Float16* Xh   = (_Float16*)p; p += ND * 2;
    _Float16* Hh   = (_Float16*)p; p += ND * 2;
    _Float16* T16  = (_Float16*)p; p += ND * 2;
    _Float16* YC   = (_Float16*)p; p += ND * 2;
    _Float16* WH   = (_Float16*)p; p += (size_t)56 * DIM * DIM * 2;
    p = (char*)(((uintptr_t)p + 15) & ~(uintptr_t)15);
    _Float16* YBUF = (_Float16*)p;

    const size_t used = (size_t)(p - (char*)d_ws);
    int nslot = (int)((ws_size - used) / (ND * 2));
    if (nslot < 1) nslot = 1;
    int CH = nslot > 12 ? 12 : nslot;
    const int nchunks = (12 + CH - 1) / CH;
    CH = (12 + nchunks - 1) / nchunks;
    _Float16* Y2 = YBUF;   // ctr2 output reuses slot 0 (stream-ordered, safe)

    const dim3 blk(256);
    const int  gnBlocks = (NROWS + 3) / 4;
    const int  cwBlocks = (int)(((size_t)56 * DIM * DIM / 4 + 255) / 256);
    const int  ixBlocks = (int)((ND / 4 + 255) / 256);

    // one-time prep
    convert_w<<<cwBlocks, blk, 0, stream>>>(W_ctr, W_ctr2, W_pre, W_suc, WH);
    init_x<<<ixBlocks, blk, 0, stream>>>(lane, X, Xh);
    hipMemsetAsync(counts, 0, NROWS * sizeof(int), stream);
    count_kernel<<<dim3(NB, 12), blk, 0, stream>>>(pidx, sidx, counts);
    scan1_kernel<<<NB, blk, 0, stream>>>(counts, offsets, bsum);
    scan2_kernel<<<1, blk, 0, stream>>>(bsum, bpre);
    scan3_kernel<<<NB, blk, 0, stream>>>(offsets, bpre, cursor);
    fill_kernel<<<dim3(NB, 12), blk, 0, stream>>>(pidx, sidx, nhp, nhs,
                                                  cursor, entries);

    for (int i = 0; i < ROUNDS; ++i) {
        // YC = x @ W_ctr[i].T
        {
            const int nwg = 391 * 2;
            gemm_p<<<dim3(nwg), blk, 0, stream>>>(Xh, WH, 48 + i, 1, YC, nwg);
        }
        // 12 message GEMMs + combine (last chunk fuses GN+ReLU -> Hh)
        for (int c0 = 0; c0 < 12; c0 += CH) {
            const int nz = (12 - c0 < CH) ? (12 - c0) : CH;
            const int nwg = 391 * 2 * nz;
            gemm_p<<<dim3(nwg), blk, 0, stream>>>(Xh, WH, i * 12 + c0, nz, YBUF, nwg);
            const bool first = (c0 == 0);
            const bool last  = (c0 + nz >= 12);
            if (first && last)
                combine_f16<1, 1><<<gnBlocks, blk, 0, stream>>>(YC, T16, YBUF,
                    offsets, entries, c0, nz, norm_w + i * DIM, norm_b + i * DIM, Hh);
            else if (first)
                combine_f16<1, 0><<<gnBlocks, blk, 0, stream>>>(YC, T16, YBUF,
                    offsets, entries, c0, nz, norm_w + i * DIM, norm_b + i * DIM, Hh);
            else if (last)
                combine_f16<0, 1><<<gnBlocks, blk, 0, stream>>>(YC, T16, YBUF,
                    offsets, entries, c0, nz, norm_w + i * DIM, norm_b + i * DIM, Hh);
            else
                combine_f16<0, 0><<<gnBlocks, blk, 0, stream>>>(YC, T16, YBUF,
                    offsets, entries, c0, nz, norm_w + i * DIM, norm_b + i * DIM, Hh);
        }
        // y = h @ W_ctr2[i].T
        {
            const int nwg = 391 * 2;
            gemm_p<<<dim3(nwg), blk, 0, stream>>>(Hh, WH, 52 + i, 1, Y2, nwg);
        }
        // x = relu(gn(y) + x)
        gn1_kernel<<<gnBlocks, blk, 0, stream>>>(Y2, c2w + i * DIM,
                                                 c2b + i * DIM, X, Xh);
    }
}